// Round 11
// baseline (178.596 us; speedup 1.0000x reference)
//
#include <hip/hip_runtime.h>
#include <hip/hip_bf16.h>
#include <math.h>

#define NPTS 100000
#define KCOMP 64

typedef float v4f __attribute__((ext_vector_type(4)));
typedef __bf16 v8bf __attribute__((ext_vector_type(8)));

// Bt fragment-native layout: Bt[cw(16)][ks(8)][n(4)][lane(64)][e(8)]
//   = B[cw*64 + n*16 + (l&15)][ks*32 + (l>>4)*8 + e]   (bf16)
// Every B fragment load = one coalesced global_load_dwordx4 (base + lane*16).
// A fragments are built straight from fp32 X (whole 64-row stripe consumed once).

// ---------- kernel 1: per-component prep (Cholesky of I+M^T M, B = L^-1 M^T) ----------
__global__ __launch_bounds__(256) void prep_comp(const float* __restrict__ M,
                                                 const float* __restrict__ pi,
                                                 __bf16* __restrict__ Bt,
                                                 float* __restrict__ cvec,
                                                 float logSA) {
    __shared__ float Ml[256][16];
    __shared__ float S[16][17];
    __shared__ float sh_logpi;
    const int k = blockIdx.x, t = threadIdx.x;

    const float4* src = (const float4*)(M + (size_t)k * 4096 + (size_t)t * 16);
    float4 a0 = src[0], a1 = src[1], a2 = src[2], a3 = src[3];
    ((float4*)Ml[t])[0] = a0; ((float4*)Ml[t])[1] = a1;
    ((float4*)Ml[t])[2] = a2; ((float4*)Ml[t])[3] = a3;

    if (t < 64) {
        float v = pi[t];
        float mx = v;
        for (int off = 32; off; off >>= 1) mx = fmaxf(mx, __shfl_xor(mx, off));
        float e = __expf(v - mx);
        float s = e;
        for (int off = 32; off; off >>= 1) s += __shfl_xor(s, off);
        if (t == 0) sh_logpi = pi[k] - mx - logf(s);
    }
    __syncthreads();

    {
        int r = t >> 4, c = t & 15;
        float s = (r == c) ? 1.0f : 0.0f;
        for (int p = 0; p < 256; ++p) s += Ml[p][r] * Ml[p][c];
        S[r][c] = s;
    }
    __syncthreads();

    for (int j = 0; j < 16; ++j) {
        if (t == 0) S[j][j] = sqrtf(S[j][j]);
        __syncthreads();
        if (t > j && t < 16) S[t][j] = S[t][j] / S[j][j];
        __syncthreads();
        {
            int r = t >> 4, c = t & 15;
            if (r > j && c > j && c <= r) S[r][c] -= S[r][j] * S[c][j];
        }
        __syncthreads();
    }

    if (t == 0) {
        float ldet = 0.0f;
        for (int j = 0; j < 16; ++j) ldet += logf(S[j][j]);
        cvec[k] = logSA - ldet + sh_logpi;
    }

    float m[16] = {a0.x, a0.y, a0.z, a0.w, a1.x, a1.y, a1.z, a1.w,
                   a2.x, a2.y, a2.z, a2.w, a3.x, a3.y, a3.z, a3.w};
    float y[16];
#pragma unroll
    for (int r = 0; r < 16; ++r) {
        float v = m[r];
#pragma unroll
        for (int q = 0; q < r; ++q) v -= S[r][q] * y[q];
        y[r] = v / S[r][r];
    }
    // fragment-native Bt write: cw=k>>2, n=k&3, lane=((t>>3)&3)*16+r, ks=t>>5, e=t&7
    const int cw = k >> 2, n = k & 3;
    const int ks = t >> 5, e = t & 7;
    const int lbase = ((t >> 3) & 3) * 16;
#pragma unroll
    for (int r = 0; r < 16; ++r) {
        const size_t off = (size_t)cw * 16384 + (size_t)ks * 2048 + (size_t)n * 512
                         + (size_t)(lbase + r) * 8 + e;
        Bt[off] = (__bf16)y[r];
    }
}

// ---------- kernel 2: GEMM + fused density + online logsumexp ----------
// 1 wave/SIMD (512 VGPR budget): A fragments pinned, B ring-prefetched from L2,
// X read directly as fp32 (no convert kernel). Zero LDS, zero barriers.
__global__ __launch_bounds__(256, 1) void gemm_density(const float* __restrict__ X,
                                                       const __bf16* __restrict__ Bt,
                                                       const float* __restrict__ cvec,
                                                       float* __restrict__ out) {
    const int st = blockIdx.x * 4 + (threadIdx.x >> 6);   // 0..1567 (392 blocks)
    const int lane = threadIdx.x & 63;
    const int lo = lane & 15, hi = lane >> 4;
    const int n0 = st * 64;

    // ---- build + pin all A fragments from fp32 X (64 loads, 128 VGPR result) ----
    v8bf af[8][4];
#pragma unroll
    for (int m = 0; m < 4; ++m) {
        const int row = min(n0 + m * 16 + lo, NPTS - 1);   // clamp: safe, real data
        const float* rp = X + (size_t)row * 256 + hi * 8;
#pragma unroll
        for (int ks = 0; ks < 8; ++ks) {
            const float4 f0 = *(const float4*)(rp + ks * 32);
            const float4 f1 = *(const float4*)(rp + ks * 32 + 4);
            v8bf v;
            v[0] = (__bf16)f0.x; v[1] = (__bf16)f0.y; v[2] = (__bf16)f0.z; v[3] = (__bf16)f0.w;
            v[4] = (__bf16)f1.x; v[5] = (__bf16)f1.y; v[6] = (__bf16)f1.z; v[7] = (__bf16)f1.w;
            af[ks][m] = v;
        }
    }

    const __bf16* Bb = Bt + lane * 8;
#define LOADB(dst, cw_, ks_) do {                                        \
    const __bf16* _p = Bb + ((size_t)(cw_) << 14) + ((size_t)(ks_) << 11); \
    dst[0] = *(const v8bf*)(_p);                                         \
    dst[1] = *(const v8bf*)(_p + 512);                                   \
    dst[2] = *(const v8bf*)(_p + 1024);                                  \
    dst[3] = *(const v8bf*)(_p + 1536);                                  \
} while (0)

    v8bf bg[4][4];          // period-4 ring, depth-2 prefetch; all indices static
    LOADB(bg[0], 0, 0);
    LOADB(bg[1], 0, 1);

    float mrun[4] = {-INFINITY, -INFINITY, -INFINITY, -INFINITY};
    float srun[4] = {0.f, 0.f, 0.f, 0.f};
    const float4* cv4 = (const float4*)cvec;

#pragma unroll 1
    for (int cw = 0; cw < 16; ++cw) {
        v4f acc[4][4] = {};
#pragma unroll
        for (int ks = 0; ks < 8; ++ks) {
            // prefetch group ks+2 (wraps into next cw's groups 0,1 at ks=6,7)
            const int pk = ks + 2;
            const int pcw = (pk < 8) ? cw : ((cw + 1) & 15);   // &15: last-iter clamp
            LOADB(bg[pk & 3], pcw, pk & 7);
#pragma unroll
            for (int m = 0; m < 4; ++m)
#pragma unroll
                for (int n = 0; n < 4; ++n)
                    acc[m][n] = __builtin_amdgcn_mfma_f32_16x16x32_bf16(
                        bg[ks & 3][n], af[ks][m], acc[m][n], 0, 0, 0);
        }

        // ---- epilogue: quad -> density -> online LSE (next-cw B loads in flight) ----
        const float4 cv = cv4[cw];
#pragma unroll
        for (int m = 0; m < 4; ++m) {
            float d[4];
#pragma unroll
            for (int n = 0; n < 4; ++n) {
                v4f qv = acc[m][n];
                float s = qv[0] * qv[0] + qv[1] * qv[1] + qv[2] * qv[2] + qv[3] * qv[3];
                s += __shfl_xor(s, 16);
                s += __shfl_xor(s, 32);
                const float c = (n == 0) ? cv.x : (n == 1) ? cv.y : (n == 2) ? cv.z : cv.w;
                d[n] = c - 128.0f * __logf(1.0f - s);
            }
            const float mt = fmaxf(fmaxf(d[0], d[1]), fmaxf(d[2], d[3]));
            const float mn = fmaxf(mrun[m], mt);
            srun[m] = srun[m] * __expf(mrun[m] - mn)
                    + __expf(d[0] - mn) + __expf(d[1] - mn)
                    + __expf(d[2] - mn) + __expf(d[3] - mn);
            mrun[m] = mn;
        }
    }
#undef LOADB

    // ---- final: per-point LSE, mask pad/clamped points, 16-group sum, one atomic ----
    float tot = 0.f;
#pragma unroll
    for (int m = 0; m < 4; ++m) {
        const int pt = n0 + m * 16 + lo;
        const float lse = mrun[m] + __logf(srun[m]);
        tot += (pt < NPTS) ? lse : 0.f;
    }
    tot += __shfl_xor(tot, 1);
    tot += __shfl_xor(tot, 2);
    tot += __shfl_xor(tot, 4);
    tot += __shfl_xor(tot, 8);
    if (lane == 0) atomicAdd(out, tot);
}

extern "C" void kernel_launch(void* const* d_in, const int* in_sizes, int n_in,
                              void* d_out, int out_size, void* d_ws, size_t ws_size,
                              hipStream_t stream) {
    const float* X  = (const float*)d_in[0];
    const float* M  = (const float*)d_in[1];
    const float* pi = (const float*)d_in[2];
    float* out = (float*)d_out;

    char* ws = (char*)d_ws;
    __bf16* Bt   = (__bf16*)ws;              // 16*16384*2 = 524,288 B
    float*  cvec = (float*)(ws + 524288);    // 256 B

    const double half_p = 128.0;
    const float logSA = (float)(lgamma(half_p) - log(2.0) - half_p * log(M_PI));

    hipMemsetAsync(d_out, 0, sizeof(float), stream);
    prep_comp<<<64, 256, 0, stream>>>(M, pi, Bt, cvec, logSA);
    gemm_density<<<392, 256, 0, stream>>>(X, Bt, cvec, out);
}